// Round 3
// baseline (314.964 us; speedup 1.0000x reference)
//
#include <hip/hip_runtime.h>
#include <hip/hip_bf16.h>
#include <math.h>

#define NP 10
#define NE 45
#define TS 16                 // timesteps per block
#define EPB (TS * NE)         // 720 edges per block
#define BLOCK 256
#define NCHUNK 12             // 12 chunks of 64 edges (768 slots, 720 active)
#define C1S 36                // c1 row stride in floats (144B: 16B-aligned, 2-way banks only)

typedef __attribute__((ext_vector_type(8))) short short8;   // 8 bf16 MFMA frag
typedef __attribute__((ext_vector_type(4))) float f32x4;

#define C2LOG2E 2.885390081777927f   // 2*log2(e) folded into layer-1/2 pre-activations

__device__ __forceinline__ float rcp_fast(float x) { return __builtin_amdgcn_rcpf(x); }

// s already scaled by 2*log2(e): tanh = 1 - 2/(2^s + 1); self-saturating
__device__ __forceinline__ float tanh_pre(float s) {
    float e = __builtin_amdgcn_exp2f(s);
    return fmaf(-2.0f, rcp_fast(e + 1.0f), 1.0f);
}

__device__ __forceinline__ short bf16_rne(float f) {
    unsigned int u = __float_as_uint(f);
    return (short)((u + 0x7fffu + ((u >> 16) & 1u)) >> 16);
}
__device__ __forceinline__ int bf16pk(float a, float b) {
    unsigned int ua = __float_as_uint(a) + 0x8000u;
    unsigned int ub = __float_as_uint(b) + 0x8000u;
    return (int)((ua >> 16) | (ub & 0xffff0000u));
}

// cross-lane helpers (no LDS memory, no conflicts)
__device__ __forceinline__ float bperm_f(int idx_bytes, float v) {
    return __int_as_float(__builtin_amdgcn_ds_bpermute(idx_bytes, __float_as_int(v)));
}
__device__ __forceinline__ float xor16_f(float v) {   // lane ^ 16 (within 32-halves: ok)
    return __int_as_float(__builtin_amdgcn_ds_swizzle(__float_as_int(v), 0x401F));
}

__global__ __launch_bounds__(BLOCK, 4) void
learn_forces_kernel(const float* __restrict__ D_V, const float* __restrict__ logm,
                    const float* __restrict__ W1, const float* __restrict__ b1,
                    const float* __restrict__ W2, const float* __restrict__ b2,
                    const float* __restrict__ W3, const float* __restrict__ b3,
                    const int* __restrict__ senders, const int* __restrict__ receivers,
                    float* __restrict__ out, int ntime)
{
    __shared__ float slm[NP];
    __shared__ int   ssnd[NE], srcv[NE];
    __shared__ float acc[TS * NP * 3];                  // 1.92 KB
    __shared__ __align__(16) float c1[NE * C1S];        // 6.48 KB: b1 + W1[3:5]·logm folded

    const int tid  = threadIdx.x;
    const int wv   = tid >> 6, lane = tid & 63;
    const int m    = lane & 15, q = lane >> 4;

    if (tid < NP) slm[tid] = fminf(12.0f, fmaxf(-12.0f, logm[tid]));
    if (tid < NE) { ssnd[tid] = senders[tid]; srcv[tid] = receivers[tid]; }
    for (int i = tid; i < TS * NP * 3; i += BLOCK) acc[i] = 0.0f;
    // time-invariant part of layer-1 pre-activation, per (edge-pair, neuron)
    for (int i = tid; i < NE * 32; i += BLOCK) {
        int le = i >> 5, n = i & 31;
        float lr = fminf(12.0f, fmaxf(-12.0f, logm[receivers[le]]));
        float ls = fminf(12.0f, fmaxf(-12.0f, logm[senders[le]]));
        c1[le * C1S + n] = (b1[n] + W1[96 + n] * lr + W1[128 + n] * ls) * C2LOG2E;
    }

    // ---- per-lane constants (wave-uniform-indexed globals -> s_load) ----
    float w1c[3][8];                      // W1 cols 8q..8q+7, k=0..2, prescaled
    #pragma unroll
    for (int k = 0; k < 3; ++k)
        #pragma unroll
        for (int j = 0; j < 8; ++j)
            w1c[k][j] = W1[k * 32 + 8 * q + j] * C2LOG2E;

    short8 a2[2];                         // A[row=out][k=in] = W2[k][out], prescaled
    #pragma unroll
    for (int t = 0; t < 2; ++t)
        #pragma unroll
        for (int j = 0; j < 8; ++j)
            a2[t][j] = bf16_rne(W2[(8 * q + j) * 32 + m + 16 * t] * C2LOG2E);

    float b2v[8];
    #pragma unroll
    for (int t = 0; t < 2; ++t)
        #pragma unroll
        for (int r = 0; r < 4; ++r)
            b2v[t * 4 + r] = b2[16 * t + 4 * q + r] * C2LOG2E;

    float w3c[8][3];                      // W3 rows {4q+r, 16+4q+r}
    #pragma unroll
    for (int r = 0; r < 4; ++r)
        #pragma unroll
        for (int c2 = 0; c2 < 3; ++c2) {
            w3c[r][c2]     = W3[(4 * q + r) * 3 + c2];
            w3c[4 + r][c2] = W3[(16 + 4 * q + r) * 3 + c2];
        }
    const float b30 = b3[0], b31 = b3[1], b32 = b3[2];

    const int bpm   = m * 4;              // bpermute base: source lane (g<<4)|m
    const int bpx32 = (lane ^ 32) * 4;    // butterfly partner across halves

    __syncthreads();

    const f32x4 zf = {0.f, 0.f, 0.f, 0.f};

    for (int c = wv; c < NCHUNK; c += 4) {
        const int  e_loc  = c * 64 + lane;
        const bool active = e_loc < EPB;
        const int  lt = e_loc / NE;                // compiler magic-div
        const int  le = e_loc - lt * NE;

        float x = 0.f, y = 0.f, z = 1.f;
        if (active) {
            const float* dv = D_V + ((long)blockIdx.x * EPB + e_loc) * 3;
            x = dv[0]; y = dv[1]; z = dv[2];
        }
        float r  = sqrtf(x * x + y * y + z * z);
        float zr = fminf(1.0f, fmaxf(-1.0f, z * rcp_fast(r)));
        float th = acosf(zr);
        float ph = atan2f(y, x);

        float e0 = b30, e1 = b31, e2 = b32;        // own-edge force accumulators

        #pragma unroll
        for (int g = 0; g < 4; ++g) {
            // fetch features of edge (16g + m) — this lane's B-column for group g
            const int idx = bpm + g * 64;
            float rg = bperm_f(idx, r);
            float tg = bperm_f(idx, th);
            float pg = bperm_f(idx, ph);
            int  leg = __builtin_amdgcn_ds_bpermute(idx, le);

            // layer 1: 8 neurons (8q..8q+7) of that edge
            const float* c1r = &c1[leg * C1S + 8 * q];
            f32x4 cA = *(const f32x4*)c1r;
            f32x4 cB = *(const f32x4*)(c1r + 4);
            float h[8];
            #pragma unroll
            for (int j = 0; j < 8; ++j) {
                float a0 = (j < 4) ? cA[j] : cB[j - 4];
                h[j] = tanh_pre(fmaf(w1c[2][j], pg,
                                fmaf(w1c[1][j], tg,
                                fmaf(w1c[0][j], rg, a0))));
            }
            // B-frag already in the right lane: k = 8q+j, n = m
            short8 bf;
            int* bi = (int*)&bf;
            bi[0] = bf16pk(h[0], h[1]); bi[1] = bf16pk(h[2], h[3]);
            bi[2] = bf16pk(h[4], h[5]); bi[3] = bf16pk(h[6], h[7]);

            // layer 2 (MFMA): D rows 4q+r (d0) and 16+4q+r (d1), col = m
            f32x4 d0 = __builtin_amdgcn_mfma_f32_16x16x32_bf16(a2[0], bf, zf, 0, 0, 0);
            f32x4 d1 = __builtin_amdgcn_mfma_f32_16x16x32_bf16(a2[1], bf, zf, 0, 0, 0);
            float t0 = tanh_pre(d0[0] + b2v[0]), t1 = tanh_pre(d0[1] + b2v[1]);
            float t2 = tanh_pre(d0[2] + b2v[2]), t3 = tanh_pre(d0[3] + b2v[3]);
            float u0 = tanh_pre(d1[0] + b2v[4]), u1 = tanh_pre(d1[1] + b2v[5]);
            float u2 = tanh_pre(d1[2] + b2v[6]), u3 = tanh_pre(d1[3] + b2v[7]);

            // layer 3 partials over this lane's 8 h2 rows
            float s0, s1, s2;
            s0 = t0 * w3c[0][0]; s1 = t0 * w3c[0][1]; s2 = t0 * w3c[0][2];
            s0 = fmaf(t1, w3c[1][0], s0); s1 = fmaf(t1, w3c[1][1], s1); s2 = fmaf(t1, w3c[1][2], s2);
            s0 = fmaf(t2, w3c[2][0], s0); s1 = fmaf(t2, w3c[2][1], s1); s2 = fmaf(t2, w3c[2][2], s2);
            s0 = fmaf(t3, w3c[3][0], s0); s1 = fmaf(t3, w3c[3][1], s1); s2 = fmaf(t3, w3c[3][2], s2);
            s0 = fmaf(u0, w3c[4][0], s0); s1 = fmaf(u0, w3c[4][1], s1); s2 = fmaf(u0, w3c[4][2], s2);
            s0 = fmaf(u1, w3c[5][0], s0); s1 = fmaf(u1, w3c[5][1], s1); s2 = fmaf(u1, w3c[5][2], s2);
            s0 = fmaf(u2, w3c[6][0], s0); s1 = fmaf(u2, w3c[6][1], s1); s2 = fmaf(u2, w3c[6][2], s2);
            s0 = fmaf(u3, w3c[7][0], s0); s1 = fmaf(u3, w3c[7][1], s1); s2 = fmaf(u3, w3c[7][2], s2);

            // butterfly over q (^16 then ^32): every lane gets the full sum
            s0 += xor16_f(s0); s1 += xor16_f(s1); s2 += xor16_f(s2);
            s0 += bperm_f(bpx32, s0); s1 += bperm_f(bpx32, s1); s2 += bperm_f(bpx32, s2);

            // group g's edges are 16g+m -> owned by lanes with q == g (own edge!)
            if (q == g) { e0 += s0; e1 += s1; e2 += s2; }
        }

        // epilogue for this lane's own edge
        float st = __sinf(e1), ct = __cosf(e1);
        float sp = __sinf(e2), cp = __cosf(e2);
        float ex = e0 * st * cp, ey = e0 * st * sp, ez = e0 * ct;
        if (active) {
            int ri = srcv[le], si = ssnd[le];
            float* ar = &acc[(lt * NP + ri) * 3];
            float* as = &acc[(lt * NP + si) * 3];
            atomicAdd(&ar[0],  ex); atomicAdd(&ar[1],  ey); atomicAdd(&ar[2],  ez);
            atomicAdd(&as[0], -ex); atomicAdd(&as[1], -ey); atomicAdd(&as[2], -ez);
        }
    }
    __syncthreads();

    const long t0g = (long)blockIdx.x * TS;
    for (int i = tid; i < TS * NP * 3; i += BLOCK) {
        int p = (i / 3) % NP;
        out[t0g * NP * 3 + i] = acc[i] * __expf(-slm[p]);
    }
}

extern "C" void kernel_launch(void* const* d_in, const int* in_sizes, int n_in,
                              void* d_out, int out_size, void* d_ws, size_t ws_size,
                              hipStream_t stream) {
    const float* D_V  = (const float*)d_in[0];
    const float* logm = (const float*)d_in[1];
    const float* W1   = (const float*)d_in[2];
    const float* b1   = (const float*)d_in[3];
    const float* W2   = (const float*)d_in[4];
    const float* b2   = (const float*)d_in[5];
    const float* W3   = (const float*)d_in[6];
    const float* b3   = (const float*)d_in[7];
    const int* senders   = (const int*)d_in[8];
    const int* receivers = (const int*)d_in[9];

    int nedges = in_sizes[8];               // 45
    int ntime  = in_sizes[0] / 3 / nedges;  // 100000

    int nblocks = (ntime + TS - 1) / TS;    // 6250
    learn_forces_kernel<<<nblocks, BLOCK, 0, stream>>>(
        D_V, logm, W1, b1, W2, b2, W3, b3, senders, receivers,
        (float*)d_out, ntime);
}

// Round 4
// 303.967 us; speedup vs baseline: 1.0362x; 1.0362x over previous
//
#include <hip/hip_runtime.h>
#include <hip/hip_bf16.h>
#include <math.h>

#define NP 10
#define NE 45
#define TS 32                      // timesteps per block
#define EPB (TS * NE)              // 1440 edges per block
#define BLOCK 256
#define NCHUNK ((EPB + 63) / 64)   // 23 chunks of 64 edge-slots

typedef __attribute__((ext_vector_type(8))) short short8;   // 8 bf16 MFMA frag
typedef __attribute__((ext_vector_type(4))) float f32x4;

#define C2LOG2E 2.885390081777927f   // 2*log2(e), folded into W1/W2/b1/b2

__device__ __forceinline__ float rcp_fast(float x) { return __builtin_amdgcn_rcpf(x); }

// s already scaled by 2*log2(e): tanh = 1 - 2/(2^s + 1); self-saturating
__device__ __forceinline__ float tanh_pre(float s) {
    float e = __builtin_amdgcn_exp2f(s);
    return fmaf(-2.0f, rcp_fast(e + 1.0f), 1.0f);
}

__device__ __forceinline__ short bf16_rne(float f) {
    unsigned int u = __float_as_uint(f);
    return (short)((u + 0x7fffu + ((u >> 16) & 1u)) >> 16);
}
__device__ __forceinline__ int bf16pk(float a, float b) {
    unsigned int ua = __float_as_uint(a) + 0x8000u;
    unsigned int ub = __float_as_uint(b) + 0x8000u;
    return (int)((ua >> 16) | (ub & 0xffff0000u));
}
__device__ __forceinline__ float bperm_f(int idx_bytes, float v) {
    return __int_as_float(__builtin_amdgcn_ds_bpermute(idx_bytes, __float_as_int(v)));
}

__global__ __launch_bounds__(BLOCK, 4) void
learn_forces_kernel(const float* __restrict__ D_V, const float* __restrict__ logm,
                    const float* __restrict__ W1, const float* __restrict__ b1,
                    const float* __restrict__ W2, const float* __restrict__ b2,
                    const float* __restrict__ W3, const float* __restrict__ b3,
                    const int* __restrict__ senders, const int* __restrict__ receivers,
                    float* __restrict__ out, int ntime)
{
    __shared__ float slm[NP], einv[NP];
    __shared__ int   ssnd[NE], srcv[NE];
    __shared__ float acc[TS * NP * 3];                  // 3.84 KB

    const int tid  = threadIdx.x;
    const int wv   = tid >> 6, lane = tid & 63;
    const int m    = lane & 15, q = lane >> 4;

    if (tid < NP) {
        float l = fminf(12.0f, fmaxf(-12.0f, logm[tid]));
        slm[tid]  = l;
        einv[tid] = __expf(-l);
    }
    if (tid < NE) { ssnd[tid] = senders[tid]; srcv[tid] = receivers[tid]; }
    for (int i = tid; i < TS * NP * 3; i += BLOCK) acc[i] = 0.0f;

    // ---- M-permuted weight fragments ------------------------------------
    // Output-neuron n = 8q + 4t + r is produced at MFMA C position 16t+4q+r
    // (lane (q,m), tile t, reg r). Hence lane (q,m) ends up holding neurons
    // 8q..8q+7 of edge-column m == exactly the B-fragment (k=8q+j, n=m) the
    // next layer needs. Layers chain in registers with no shuffles.
    const int nm = 8 * (m >> 2) + (m & 3);   // + 4t below
    short8 a1[2], a2[2], a3;
    float  b1v[8], b2v[8];
    #pragma unroll
    for (int t = 0; t < 2; ++t) {
        const int n = nm + 4 * t;
        #pragma unroll
        for (int j = 0; j < 8; ++j) {
            int k = 8 * q + j;
            a1[t][j] = (k < 5) ? bf16_rne(W1[k * 32 + n] * C2LOG2E) : (short)0;
            a2[t][j] = bf16_rne(W2[k * 32 + n] * C2LOG2E);
        }
        #pragma unroll
        for (int r = 0; r < 4; ++r) {
            int nn = 8 * q + 4 * t + r;          // neuron at (t, r) for this lane
            b1v[t * 4 + r] = b1[nn] * C2LOG2E;
            b2v[t * 4 + r] = b2[nn] * C2LOG2E;
        }
    }
    #pragma unroll
    for (int j = 0; j < 8; ++j)                  // L3: natural M (rows 0..2)
        a3[j] = (m < 3) ? bf16_rne(W3[(8 * q + j) * 3 + m]) : (short)0;
    const float b30 = b3[0], b31 = b3[1], b32 = b3[2];

    const int bpm = m * 4;                       // bpermute base (src lane 16g+m)
    __syncthreads();

    const f32x4 zf = {0.f, 0.f, 0.f, 0.f};

    for (int c = wv; c < NCHUNK; c += 4) {
        const int  e_loc  = c * 64 + lane;
        const bool active = e_loc < EPB;
        const int  lt = e_loc / NE;
        const int  le = e_loc - lt * NE;
        const int  ri = srcv[le], si = ssnd[le];
        const float lmr = slm[ri], lms = slm[si];

        float x = 0.f, y = 0.f, z = 1.f;         // inactive: finite dummy
        if (active) {
            const float* dv = D_V + ((long)blockIdx.x * EPB + e_loc) * 3;
            x = dv[0]; y = dv[1]; z = dv[2];
        }
        float r  = sqrtf(x * x + y * y + z * z);
        float zr = fminf(1.0f, fmaxf(-1.0f, z * rcp_fast(r)));
        float th = acosf(zr);
        float ph = atan2f(y, x);

        float e0 = b30, e1 = b31, e2 = b32;      // own-edge force accumulators

        #pragma unroll
        for (int g = 0; g < 4; ++g) {
            // features of edge (16g + m) -> this lane's B-column for group g
            const int idx = bpm + g * 64;
            float rg = bperm_f(idx, r);
            float tg = bperm_f(idx, th);
            float pg = bperm_f(idx, ph);
            float mr = bperm_f(idx, lmr);
            float ms = bperm_f(idx, lms);

            // L1 B-frag: k=0..4 live only in q==0 lanes
            short8 bf1 = 0;
            if (q == 0) {
                int* bi = (int*)&bf1;
                bi[0] = bf16pk(rg, tg);
                bi[1] = bf16pk(pg, mr);
                bi[2] = bf16pk(ms, 0.f);
            }
            f32x4 d0 = __builtin_amdgcn_mfma_f32_16x16x32_bf16(a1[0], bf1, zf, 0, 0, 0);
            f32x4 d1 = __builtin_amdgcn_mfma_f32_16x16x32_bf16(a1[1], bf1, zf, 0, 0, 0);

            // h1 neurons 8q+j of edge m, already B-frag-ordered
            short8 bh1;
            {
                int* hb = (int*)&bh1;
                float h0 = tanh_pre(d0[0] + b1v[0]), h1_ = tanh_pre(d0[1] + b1v[1]);
                float h2 = tanh_pre(d0[2] + b1v[2]), h3 = tanh_pre(d0[3] + b1v[3]);
                float h4 = tanh_pre(d1[0] + b1v[4]), h5 = tanh_pre(d1[1] + b1v[5]);
                float h6 = tanh_pre(d1[2] + b1v[6]), h7 = tanh_pre(d1[3] + b1v[7]);
                hb[0] = bf16pk(h0, h1_); hb[1] = bf16pk(h2, h3);
                hb[2] = bf16pk(h4, h5);  hb[3] = bf16pk(h6, h7);
            }
            d0 = __builtin_amdgcn_mfma_f32_16x16x32_bf16(a2[0], bh1, zf, 0, 0, 0);
            d1 = __builtin_amdgcn_mfma_f32_16x16x32_bf16(a2[1], bh1, zf, 0, 0, 0);

            short8 bh2;
            {
                int* hb = (int*)&bh2;
                float h0 = tanh_pre(d0[0] + b2v[0]), h1_ = tanh_pre(d0[1] + b2v[1]);
                float h2 = tanh_pre(d0[2] + b2v[2]), h3 = tanh_pre(d0[3] + b2v[3]);
                float h4 = tanh_pre(d1[0] + b2v[4]), h5 = tanh_pre(d1[1] + b2v[5]);
                float h6 = tanh_pre(d1[2] + b2v[6]), h7 = tanh_pre(d1[3] + b2v[7]);
                hb[0] = bf16pk(h0, h1_); hb[1] = bf16pk(h2, h3);
                hb[2] = bf16pk(h4, h5);  hb[3] = bf16pk(h6, h7);
            }
            // L3: rows 0..2 of D live in lanes q==0; pull to all lanes of col m
            f32x4 d3 = __builtin_amdgcn_mfma_f32_16x16x32_bf16(a3, bh2, zf, 0, 0, 0);
            float s0 = bperm_f(bpm, d3[0]);
            float s1 = bperm_f(bpm, d3[1]);
            float s2 = bperm_f(bpm, d3[2]);
            if (q == g) { e0 += s0; e1 += s1; e2 += s2; }
        }

        // epilogue for this lane's own edge: sph -> cart + signed scatter
        float st = __sinf(e1), ct = __cosf(e1);
        float sp = __sinf(e2), cp = __cosf(e2);
        float ex = e0 * st * cp, ey = e0 * st * sp, ez = e0 * ct;
        if (active) {
            float* ar = &acc[(lt * NP + ri) * 3];
            float* as = &acc[(lt * NP + si) * 3];
            atomicAdd(&ar[0],  ex); atomicAdd(&ar[1],  ey); atomicAdd(&ar[2],  ez);
            atomicAdd(&as[0], -ex); atomicAdd(&as[1], -ey); atomicAdd(&as[2], -ez);
        }
    }
    __syncthreads();

    const long t0g = (long)blockIdx.x * TS;
    for (int i = tid; i < TS * NP * 3; i += BLOCK) {
        int p = (i / 3) % NP;
        out[t0g * NP * 3 + i] = acc[i] * einv[p];
    }
}

extern "C" void kernel_launch(void* const* d_in, const int* in_sizes, int n_in,
                              void* d_out, int out_size, void* d_ws, size_t ws_size,
                              hipStream_t stream) {
    const float* D_V  = (const float*)d_in[0];
    const float* logm = (const float*)d_in[1];
    const float* W1   = (const float*)d_in[2];
    const float* b1   = (const float*)d_in[3];
    const float* W2   = (const float*)d_in[4];
    const float* b2   = (const float*)d_in[5];
    const float* W3   = (const float*)d_in[6];
    const float* b3   = (const float*)d_in[7];
    const int* senders   = (const int*)d_in[8];
    const int* receivers = (const int*)d_in[9];

    int nedges = in_sizes[8];               // 45
    int ntime  = in_sizes[0] / 3 / nedges;  // 100000

    int nblocks = (ntime + TS - 1) / TS;    // 3125
    learn_forces_kernel<<<nblocks, BLOCK, 0, stream>>>(
        D_V, logm, W1, b1, W2, b2, W3, b3, senders, receivers,
        (float*)d_out, ntime);
}

// Round 5
// 295.766 us; speedup vs baseline: 1.0649x; 1.0277x over previous
//
#include <hip/hip_runtime.h>
#include <hip/hip_bf16.h>
#include <math.h>

#define NP 10
#define NE 45
#define TS 32                      // timesteps per block
#define EPB (TS * NE)              // 1440 edges per block
#define BLOCK 256
#define NCHUNK ((EPB + 63) / 64)   // 23 chunks of 64 edge-slots

typedef __attribute__((ext_vector_type(8))) short short8;   // 8 bf16 MFMA frag
typedef __attribute__((ext_vector_type(4))) float f32x4;

#define C2LOG2E 2.885390081777927f   // 2*log2(e), folded into W1/W2/b1/b2

__device__ __forceinline__ float rcp_fast(float x) { return __builtin_amdgcn_rcpf(x); }

// s already scaled by 2*log2(e) and bias-included: tanh = 1 - 2/(2^s + 1)
__device__ __forceinline__ float tanh_pre(float s) {
    float e = __builtin_amdgcn_exp2f(s);
    return fmaf(-2.0f, rcp_fast(e + 1.0f), 1.0f);
}

__device__ __forceinline__ short bf16_rne(float f) {
    unsigned int u = __float_as_uint(f);
    return (short)((u + 0x7fffu + ((u >> 16) & 1u)) >> 16);
}
__device__ __forceinline__ int bf16pk(float a, float b) {
    unsigned int ua = __float_as_uint(a) + 0x8000u;
    unsigned int ub = __float_as_uint(b) + 0x8000u;
    return (int)((ua >> 16) | (ub & 0xffff0000u));
}
__device__ __forceinline__ float bperm_f(int idx_bytes, float v) {
    return __int_as_float(__builtin_amdgcn_ds_bpermute(idx_bytes, __float_as_int(v)));
}

__global__ __launch_bounds__(BLOCK, 4) void
learn_forces_kernel(const float* __restrict__ D_V, const float* __restrict__ logm,
                    const float* __restrict__ W1, const float* __restrict__ b1,
                    const float* __restrict__ W2, const float* __restrict__ b2,
                    const float* __restrict__ W3, const float* __restrict__ b3,
                    const int* __restrict__ senders, const int* __restrict__ receivers,
                    float* __restrict__ out, int ntime)
{
    __shared__ float slm[NP], einv[NP];
    __shared__ int   ssnd[NE], srcv[NE];
    __shared__ float acc[TS * NP * 3];                  // 3.84 KB

    const int tid  = threadIdx.x;
    const int wv   = tid >> 6, lane = tid & 63;
    const int m    = lane & 15, q = lane >> 4;

    if (tid < NP) {
        float l = fminf(12.0f, fmaxf(-12.0f, logm[tid]));
        slm[tid]  = l;
        einv[tid] = __expf(-l);
    }
    if (tid < NE) { ssnd[tid] = senders[tid]; srcv[tid] = receivers[tid]; }
    for (int i = tid; i < TS * NP * 3; i += BLOCK) acc[i] = 0.0f;

    // ---- M-permuted weight fragments (layout proven in R4) --------------
    // Output-neuron n = 8q+4t+r is produced at MFMA C position (tile t, reg r,
    // lane (q,m)) => each lane ends holding exactly its next-layer B-fragment.
    const int nm = 8 * (m >> 2) + (m & 3);   // + 4t below
    short8 a1[2], a2[2], a3;
    f32x4  cb1[2], cb2[2], cb3;              // biases preloaded as MFMA C-init
    #pragma unroll
    for (int t = 0; t < 2; ++t) {
        const int n = nm + 4 * t;
        #pragma unroll
        for (int j = 0; j < 8; ++j) {
            int k = 8 * q + j;
            a1[t][j] = (k < 5) ? bf16_rne(W1[k * 32 + n] * C2LOG2E) : (short)0;
            a2[t][j] = bf16_rne(W2[k * 32 + n] * C2LOG2E);
        }
        #pragma unroll
        for (int r = 0; r < 4; ++r) {
            int nn = 8 * q + 4 * t + r;
            cb1[t][r] = b1[nn] * C2LOG2E;
            cb2[t][r] = b2[nn] * C2LOG2E;
        }
    }
    #pragma unroll
    for (int j = 0; j < 8; ++j)
        a3[j] = (m < 3) ? bf16_rne(W3[(8 * q + j) * 3 + m]) : (short)0;
    #pragma unroll
    for (int r = 0; r < 4; ++r) {
        int row = 4 * q + r;                 // C row for L3
        cb3[r] = (row < 3) ? b3[row] : 0.0f;
    }

    const int bpm = m * 4;                   // bpermute idx: pull from lane (g<<4)|m
    __syncthreads();

    // software prefetch of first chunk's D_V
    const long ebase = (long)blockIdx.x * EPB;
    float xn = 0.f, yn = 0.f, zn = 1.f;
    {
        int e0i = wv * 64 + lane;
        if (e0i < EPB) {
            const float* dv = D_V + (ebase + e0i) * 3;
            xn = dv[0]; yn = dv[1]; zn = dv[2];
        }
    }

    for (int c = wv; c < NCHUNK; c += 4) {
        const int  e_loc  = c * 64 + lane;
        const bool active = e_loc < EPB;
        const int  lt = e_loc / NE;
        const int  le = e_loc - lt * NE;
        const int  ri = srcv[le], si = ssnd[le];

        float x = xn, y = yn, z = zn;
        // prefetch next chunk
        xn = 0.f; yn = 0.f; zn = 1.f;
        {
            int enx = (c + 4) * 64 + lane;
            if (c + 4 < NCHUNK && enx < EPB) {
                const float* dv = D_V + (ebase + enx) * 3;
                xn = dv[0]; yn = dv[1]; zn = dv[2];
            }
        }

        const float lmr = slm[ri], lms = slm[si];
        float r  = sqrtf(x * x + y * y + z * z);
        float zr = fminf(1.0f, fmaxf(-1.0f, z * rcp_fast(r)));
        float th = acosf(zr);
        float ph = atan2f(y, x);

        // ---- S1: all cross-lane feature pulls (20 bperms, one latency hop)
        float rg[4], tg[4], pg[4], mr[4], ms[4];
        #pragma unroll
        for (int g = 0; g < 4; ++g) {
            const int idx = bpm + g * 64;
            rg[g] = bperm_f(idx, r);
            tg[g] = bperm_f(idx, th);
            pg[g] = bperm_f(idx, ph);
            mr[g] = bperm_f(idx, lmr);
            ms[g] = bperm_f(idx, lms);
        }

        // ---- S2: build L1 B-frags, 8 MFMAs back-to-back -----------------
        f32x4 d0[4], d1[4];
        #pragma unroll
        for (int g = 0; g < 4; ++g) {
            short8 bf1 = 0;
            if (q == 0) {
                int* bi = (int*)&bf1;
                bi[0] = bf16pk(rg[g], tg[g]);
                bi[1] = bf16pk(pg[g], mr[g]);
                bi[2] = bf16pk(ms[g], 0.f);
            }
            d0[g] = __builtin_amdgcn_mfma_f32_16x16x32_bf16(a1[0], bf1, cb1[0], 0, 0, 0);
            d1[g] = __builtin_amdgcn_mfma_f32_16x16x32_bf16(a1[1], bf1, cb1[1], 0, 0, 0);
        }

        // ---- S3: tanh + pack + L2 MFMAs (pipelines across groups) -------
        #pragma unroll
        for (int g = 0; g < 4; ++g) {
            short8 bh;
            int* hb = (int*)&bh;
            float h0 = tanh_pre(d0[g][0]), h1 = tanh_pre(d0[g][1]);
            float h2 = tanh_pre(d0[g][2]), h3 = tanh_pre(d0[g][3]);
            float h4 = tanh_pre(d1[g][0]), h5 = tanh_pre(d1[g][1]);
            float h6 = tanh_pre(d1[g][2]), h7 = tanh_pre(d1[g][3]);
            hb[0] = bf16pk(h0, h1); hb[1] = bf16pk(h2, h3);
            hb[2] = bf16pk(h4, h5); hb[3] = bf16pk(h6, h7);
            d0[g] = __builtin_amdgcn_mfma_f32_16x16x32_bf16(a2[0], bh, cb2[0], 0, 0, 0);
            d1[g] = __builtin_amdgcn_mfma_f32_16x16x32_bf16(a2[1], bh, cb2[1], 0, 0, 0);
        }

        // ---- S4: tanh + pack + L3 MFMAs ---------------------------------
        f32x4 d3[4];
        #pragma unroll
        for (int g = 0; g < 4; ++g) {
            short8 bh;
            int* hb = (int*)&bh;
            float h0 = tanh_pre(d0[g][0]), h1 = tanh_pre(d0[g][1]);
            float h2 = tanh_pre(d0[g][2]), h3 = tanh_pre(d0[g][3]);
            float h4 = tanh_pre(d1[g][0]), h5 = tanh_pre(d1[g][1]);
            float h6 = tanh_pre(d1[g][2]), h7 = tanh_pre(d1[g][3]);
            hb[0] = bf16pk(h0, h1); hb[1] = bf16pk(h2, h3);
            hb[2] = bf16pk(h4, h5); hb[3] = bf16pk(h6, h7);
            d3[g] = __builtin_amdgcn_mfma_f32_16x16x32_bf16(a3, bh, cb3, 0, 0, 0);
        }

        // ---- S5: batch-pull L3 rows 0..2 from q==0 lanes (12 bperms) ----
        float s0[4], s1[4], s2[4];
        #pragma unroll
        for (int g = 0; g < 4; ++g) {
            s0[g] = bperm_f(bpm, d3[g][0]);
            s1[g] = bperm_f(bpm, d3[g][1]);
            s2[g] = bperm_f(bpm, d3[g][2]);
        }
        // own edge is group q: cndmask select tree
        float e0 = (q & 2) ? ((q & 1) ? s0[3] : s0[2]) : ((q & 1) ? s0[1] : s0[0]);
        float e1 = (q & 2) ? ((q & 1) ? s1[3] : s1[2]) : ((q & 1) ? s1[1] : s1[0]);
        float e2 = (q & 2) ? ((q & 1) ? s2[3] : s2[2]) : ((q & 1) ? s2[1] : s2[0]);

        // ---- epilogue: sph -> cart + signed scatter ---------------------
        float st = __sinf(e1), ct = __cosf(e1);
        float sp = __sinf(e2), cp = __cosf(e2);
        float ex = e0 * st * cp, ey = e0 * st * sp, ez = e0 * ct;
        if (active) {
            float* ar = &acc[(lt * NP + ri) * 3];
            float* as = &acc[(lt * NP + si) * 3];
            atomicAdd(&ar[0],  ex); atomicAdd(&ar[1],  ey); atomicAdd(&ar[2],  ez);
            atomicAdd(&as[0], -ex); atomicAdd(&as[1], -ey); atomicAdd(&as[2], -ez);
        }
    }
    __syncthreads();

    const long t0g = (long)blockIdx.x * TS;
    for (int i = tid; i < TS * NP * 3; i += BLOCK) {
        int p = (i / 3) % NP;
        out[t0g * NP * 3 + i] = acc[i] * einv[p];
    }
}

extern "C" void kernel_launch(void* const* d_in, const int* in_sizes, int n_in,
                              void* d_out, int out_size, void* d_ws, size_t ws_size,
                              hipStream_t stream) {
    const float* D_V  = (const float*)d_in[0];
    const float* logm = (const float*)d_in[1];
    const float* W1   = (const float*)d_in[2];
    const float* b1   = (const float*)d_in[3];
    const float* W2   = (const float*)d_in[4];
    const float* b2   = (const float*)d_in[5];
    const float* W3   = (const float*)d_in[6];
    const float* b3   = (const float*)d_in[7];
    const int* senders   = (const int*)d_in[8];
    const int* receivers = (const int*)d_in[9];

    int nedges = in_sizes[8];               // 45
    int ntime  = in_sizes[0] / 3 / nedges;  // 100000

    int nblocks = (ntime + TS - 1) / TS;    // 3125
    learn_forces_kernel<<<nblocks, BLOCK, 0, stream>>>(
        D_V, logm, W1, b1, W2, b2, W3, b3, senders, receivers,
        (float*)d_out, ntime);
}

// Round 6
// 216.149 us; speedup vs baseline: 1.4572x; 1.3683x over previous
//
#include <hip/hip_runtime.h>
#include <hip/hip_bf16.h>
#include <math.h>

#define NP 10
#define NE 45
#define TS 16                      // timesteps per block
#define EPB (TS * NE)              // 720 edges per block
#define BLOCK 256
#define NCHUNK ((EPB + 63) / 64)   // 12 chunks of 64 edge-slots

typedef __attribute__((ext_vector_type(8))) short short8;   // 8 bf16 MFMA frag
typedef __attribute__((ext_vector_type(4))) float f32x4;

#define C2LOG2E 2.885390081777927f   // 2*log2(e), folded into W1/W2/b1/b2

__device__ __forceinline__ float rcp_fast(float x) { return __builtin_amdgcn_rcpf(x); }

// s already scaled by 2*log2(e) and bias-included: tanh = 1 - 2/(2^s + 1)
__device__ __forceinline__ float tanh_pre(float s) {
    float e = __builtin_amdgcn_exp2f(s);
    return fmaf(-2.0f, rcp_fast(e + 1.0f), 1.0f);
}

__device__ __forceinline__ short bf16_rne(float f) {
    unsigned int u = __float_as_uint(f);
    return (short)((u + 0x7fffu + ((u >> 16) & 1u)) >> 16);
}
__device__ __forceinline__ int bf16pk(float a, float b) {
    unsigned int ua = __float_as_uint(a) + 0x8000u;
    unsigned int ub = __float_as_uint(b) + 0x8000u;
    return (int)((ua >> 16) | (ub & 0xffff0000u));
}
__device__ __forceinline__ float bperm_f(int idx_bytes, float v) {
    return __int_as_float(__builtin_amdgcn_ds_bpermute(idx_bytes, __float_as_int(v)));
}

__global__ __launch_bounds__(BLOCK, 4) void
learn_forces_kernel(const float* __restrict__ D_V, const float* __restrict__ logm,
                    const float* __restrict__ W1, const float* __restrict__ b1,
                    const float* __restrict__ W2, const float* __restrict__ b2,
                    const float* __restrict__ W3, const float* __restrict__ b3,
                    const int* __restrict__ senders, const int* __restrict__ receivers,
                    float* __restrict__ out, int ntime)
{
    __shared__ float slm[NP], einv[NP];
    __shared__ int   ssnd[NE], srcv[NE];
    __shared__ int   stab[NP * 9];            // signed edge list per planet: +-(e+1)
    __shared__ float secart[3][EPB];          // SoA cartesian edge forces (8.64 KB)

    const int tid  = threadIdx.x;
    const int wv   = tid >> 6, lane = tid & 63;
    const int m    = lane & 15, q = lane >> 4;

    if (tid < NP) {
        float l = fminf(12.0f, fmaxf(-12.0f, logm[tid]));
        slm[tid]  = l;
        einv[tid] = __expf(-l);
    }
    if (tid < NE) { ssnd[tid] = senders[tid]; srcv[tid] = receivers[tid]; }
    // per-planet signed edge table: receiver -> +(e+1), sender -> -(e+1); 9 each
    if (tid < NP) {
        int cnt = 0;
        for (int e = 0; e < NE; ++e) {
            if (receivers[e] == tid) stab[tid * 9 + cnt++] =  (e + 1);
            if (senders[e]   == tid) stab[tid * 9 + cnt++] = -(e + 1);
        }
        for (; cnt < 9; ++cnt) stab[tid * 9 + cnt] = 0;   // safety (shouldn't happen)
    }

    // ---- M-permuted weight fragments (layout proven in R4) --------------
    const int nm = 8 * (m >> 2) + (m & 3);   // + 4t below
    short8 a1[2], a2[2], a3;
    f32x4  cb1[2], cb2[2], cb3;              // biases preloaded as MFMA C-init
    #pragma unroll
    for (int t = 0; t < 2; ++t) {
        const int n = nm + 4 * t;
        #pragma unroll
        for (int j = 0; j < 8; ++j) {
            int k = 8 * q + j;
            a1[t][j] = (k < 5) ? bf16_rne(W1[k * 32 + n] * C2LOG2E) : (short)0;
            a2[t][j] = bf16_rne(W2[k * 32 + n] * C2LOG2E);
        }
        #pragma unroll
        for (int r = 0; r < 4; ++r) {
            int nn = 8 * q + 4 * t + r;
            cb1[t][r] = b1[nn] * C2LOG2E;
            cb2[t][r] = b2[nn] * C2LOG2E;
        }
    }
    #pragma unroll
    for (int j = 0; j < 8; ++j)
        a3[j] = (m < 3) ? bf16_rne(W3[(8 * q + j) * 3 + m]) : (short)0;
    #pragma unroll
    for (int r = 0; r < 4; ++r) {
        int row = 4 * q + r;
        cb3[r] = (row < 3) ? b3[row] : 0.0f;
    }

    const int bpm = m * 4;                   // bpermute idx: pull from lane (g<<4)|m
    __syncthreads();

    // software prefetch of first chunk's D_V
    const long ebase = (long)blockIdx.x * EPB;
    float xn = 0.f, yn = 0.f, zn = 1.f;
    {
        int e0i = wv * 64 + lane;
        if (e0i < EPB) {
            const float* dv = D_V + (ebase + e0i) * 3;
            xn = dv[0]; yn = dv[1]; zn = dv[2];
        }
    }

    for (int c = wv; c < NCHUNK; c += 4) {
        const int  e_loc  = c * 64 + lane;
        const bool active = e_loc < EPB;

        float x = xn, y = yn, z = zn;
        // prefetch next chunk
        xn = 0.f; yn = 0.f; zn = 1.f;
        {
            int enx = (c + 4) * 64 + lane;
            if (c + 4 < NCHUNK && enx < EPB) {
                const float* dv = D_V + (ebase + enx) * 3;
                xn = dv[0]; yn = dv[1]; zn = dv[2];
            }
        }

        const int le = e_loc % NE;           // only for feature masses
        const float lmr = slm[srcv[le]], lms = slm[ssnd[le]];
        float r  = sqrtf(x * x + y * y + z * z);
        float zr = fminf(1.0f, fmaxf(-1.0f, z * rcp_fast(r)));
        float th = acosf(zr);
        float ph = atan2f(y, x);

        // ---- S1: all cross-lane feature pulls (20 bperms, one latency hop)
        float rg[4], tg[4], pg[4], mr[4], ms[4];
        #pragma unroll
        for (int g = 0; g < 4; ++g) {
            const int idx = bpm + g * 64;
            rg[g] = bperm_f(idx, r);
            tg[g] = bperm_f(idx, th);
            pg[g] = bperm_f(idx, ph);
            mr[g] = bperm_f(idx, lmr);
            ms[g] = bperm_f(idx, lms);
        }

        // ---- S2: L1 MFMAs ----------------------------------------------
        f32x4 d0[4], d1[4];
        #pragma unroll
        for (int g = 0; g < 4; ++g) {
            short8 bf1 = 0;
            if (q == 0) {
                int* bi = (int*)&bf1;
                bi[0] = bf16pk(rg[g], tg[g]);
                bi[1] = bf16pk(pg[g], mr[g]);
                bi[2] = bf16pk(ms[g], 0.f);
            }
            d0[g] = __builtin_amdgcn_mfma_f32_16x16x32_bf16(a1[0], bf1, cb1[0], 0, 0, 0);
            d1[g] = __builtin_amdgcn_mfma_f32_16x16x32_bf16(a1[1], bf1, cb1[1], 0, 0, 0);
        }

        // ---- S3: tanh + L2 MFMAs ---------------------------------------
        #pragma unroll
        for (int g = 0; g < 4; ++g) {
            short8 bh;
            int* hb = (int*)&bh;
            float h0 = tanh_pre(d0[g][0]), h1 = tanh_pre(d0[g][1]);
            float h2 = tanh_pre(d0[g][2]), h3 = tanh_pre(d0[g][3]);
            float h4 = tanh_pre(d1[g][0]), h5 = tanh_pre(d1[g][1]);
            float h6 = tanh_pre(d1[g][2]), h7 = tanh_pre(d1[g][3]);
            hb[0] = bf16pk(h0, h1); hb[1] = bf16pk(h2, h3);
            hb[2] = bf16pk(h4, h5); hb[3] = bf16pk(h6, h7);
            d0[g] = __builtin_amdgcn_mfma_f32_16x16x32_bf16(a2[0], bh, cb2[0], 0, 0, 0);
            d1[g] = __builtin_amdgcn_mfma_f32_16x16x32_bf16(a2[1], bh, cb2[1], 0, 0, 0);
        }

        // ---- S4: tanh + L3 MFMAs ---------------------------------------
        f32x4 d3[4];
        #pragma unroll
        for (int g = 0; g < 4; ++g) {
            short8 bh;
            int* hb = (int*)&bh;
            float h0 = tanh_pre(d0[g][0]), h1 = tanh_pre(d0[g][1]);
            float h2 = tanh_pre(d0[g][2]), h3 = tanh_pre(d0[g][3]);
            float h4 = tanh_pre(d1[g][0]), h5 = tanh_pre(d1[g][1]);
            float h6 = tanh_pre(d1[g][2]), h7 = tanh_pre(d1[g][3]);
            hb[0] = bf16pk(h0, h1); hb[1] = bf16pk(h2, h3);
            hb[2] = bf16pk(h4, h5); hb[3] = bf16pk(h6, h7);
            d3[g] = __builtin_amdgcn_mfma_f32_16x16x32_bf16(a3, bh, cb3, 0, 0, 0);
        }

        // ---- S5: pull L3 rows 0..2 to owning lanes, select own group ----
        float s0[4], s1[4], s2[4];
        #pragma unroll
        for (int g = 0; g < 4; ++g) {
            s0[g] = bperm_f(bpm, d3[g][0]);
            s1[g] = bperm_f(bpm, d3[g][1]);
            s2[g] = bperm_f(bpm, d3[g][2]);
        }
        float e0 = (q & 2) ? ((q & 1) ? s0[3] : s0[2]) : ((q & 1) ? s0[1] : s0[0]);
        float e1 = (q & 2) ? ((q & 1) ? s1[3] : s1[2]) : ((q & 1) ? s1[1] : s1[0]);
        float e2 = (q & 2) ? ((q & 1) ? s2[3] : s2[2]) : ((q & 1) ? s2[1] : s2[0]);

        // ---- sph -> cart, plain SoA LDS store (no atomics) --------------
        float st = __sinf(e1), ct = __cosf(e1);
        float sp = __sinf(e2), cp = __cosf(e2);
        if (active) {
            secart[0][e_loc] = e0 * st * cp;
            secart[1][e_loc] = e0 * st * sp;
            secart[2][e_loc] = e0 * ct;
        }
    }
    __syncthreads();

    // ---- table-driven signed gather-sum: one (t, planet, comp) per thread
    const long t0g = (long)blockIdx.x * TS;
    for (int i = tid; i < TS * NP * 3; i += BLOCK) {
        int t  = i / (NP * 3);
        int pc = i - t * (NP * 3);
        int p  = pc / 3;
        int cc = pc - p * 3;
        const float* row = &secart[cc][t * NE];
        float s = 0.0f;
        #pragma unroll
        for (int j = 0; j < 9; ++j) {
            int es = stab[p * 9 + j];
            int e  = (es < 0 ? -es : es) - 1;
            float v = row[e];
            s += (es > 0) ? v : -v;
        }
        out[t0g * NP * 3 + i] = s * einv[p];   // contiguous 480-float range
    }
}

extern "C" void kernel_launch(void* const* d_in, const int* in_sizes, int n_in,
                              void* d_out, int out_size, void* d_ws, size_t ws_size,
                              hipStream_t stream) {
    const float* D_V  = (const float*)d_in[0];
    const float* logm = (const float*)d_in[1];
    const float* W1   = (const float*)d_in[2];
    const float* b1   = (const float*)d_in[3];
    const float* W2   = (const float*)d_in[4];
    const float* b2   = (const float*)d_in[5];
    const float* W3   = (const float*)d_in[6];
    const float* b3   = (const float*)d_in[7];
    const int* senders   = (const int*)d_in[8];
    const int* receivers = (const int*)d_in[9];

    int nedges = in_sizes[8];               // 45
    int ntime  = in_sizes[0] / 3 / nedges;  // 100000

    int nblocks = (ntime + TS - 1) / TS;    // 6250
    learn_forces_kernel<<<nblocks, BLOCK, 0, stream>>>(
        D_V, logm, W1, b1, W2, b2, W3, b3, senders, receivers,
        (float*)d_out, ntime);
}